// Round 1
// baseline (3530.173 us; speedup 1.0000x reference)
//
#include <hip/hip_runtime.h>
#include <math.h>

#define T_SEQ  2048
#define DMODEL 2048
#define NHEADS 16
#define HDIM   128
#define MROWS  4096   // B*T

// ---------------------------------------------------------------------------
// GEMM: C[M,N] = A[M,K] @ B[K,N] + bias[N]
// 128x128 tile, BK=16, 256 threads, 8x8 register micro-tile, float4 LDS.
// ---------------------------------------------------------------------------
__global__ __launch_bounds__(256) void gemm_bias_kernel(
    const float* __restrict__ A, const float* __restrict__ Bw,
    const float* __restrict__ bias, float* __restrict__ C,
    int M, int N, int K)
{
  __shared__ float As[16][128];   // As[k][m]
  __shared__ float Bs[16][128];   // Bs[k][n]
  const int tid = threadIdx.x;
  const int tx = tid & 15, ty = tid >> 4;
  const int am = tid & 127, ak4 = tid >> 7;   // A-load: row am, k-chunk ak4 (0..1)
  const int krow = tid >> 5, bn4 = tid & 31;  // B-load: k-row, n-float4

  const float* Ag = A + (size_t)(blockIdx.y * 128 + am) * K;
  const float* Bg = Bw + (size_t)blockIdx.x * 128 + bn4 * 4;

  float acc[8][8];
#pragma unroll
  for (int i = 0; i < 8; ++i)
#pragma unroll
    for (int j = 0; j < 8; ++j) acc[i][j] = 0.f;

  for (int kk = 0; kk < K; kk += 16) {
    float4 a0 = *(const float4*)(Ag + kk + ak4 * 4);
    float4 a1 = *(const float4*)(Ag + kk + ak4 * 4 + 8);
    float4 b0 = *(const float4*)(Bg + (size_t)(kk + krow) * N);
    float4 b1 = *(const float4*)(Bg + (size_t)(kk + krow + 8) * N);
    __syncthreads();
    As[ak4*4+0][am]  = a0.x; As[ak4*4+1][am]  = a0.y;
    As[ak4*4+2][am]  = a0.z; As[ak4*4+3][am]  = a0.w;
    As[ak4*4+8][am]  = a1.x; As[ak4*4+9][am]  = a1.y;
    As[ak4*4+10][am] = a1.z; As[ak4*4+11][am] = a1.w;
    *(float4*)&Bs[krow][bn4*4]     = b0;
    *(float4*)&Bs[krow+8][bn4*4]   = b1;
    __syncthreads();
#pragma unroll
    for (int k = 0; k < 16; ++k) {
      float4 aLo = *(const float4*)&As[k][ty*8];
      float4 aHi = *(const float4*)&As[k][ty*8+4];
      float4 bLo = *(const float4*)&Bs[k][tx*8];
      float4 bHi = *(const float4*)&Bs[k][tx*8+4];
      float ar[8] = {aLo.x,aLo.y,aLo.z,aLo.w,aHi.x,aHi.y,aHi.z,aHi.w};
      float br[8] = {bLo.x,bLo.y,bLo.z,bLo.w,bHi.x,bHi.y,bHi.z,bHi.w};
#pragma unroll
      for (int i = 0; i < 8; ++i)
#pragma unroll
        for (int j = 0; j < 8; ++j) acc[i][j] = fmaf(ar[i], br[j], acc[i][j]);
    }
  }

  const int row0 = blockIdx.y*128 + ty*8;
  const int col0 = blockIdx.x*128 + tx*8;
  float4 bias0 = *(const float4*)(bias + col0);
  float4 bias1 = *(const float4*)(bias + col0 + 4);
#pragma unroll
  for (int i = 0; i < 8; ++i) {
    float4 o0 = { acc[i][0]+bias0.x, acc[i][1]+bias0.y,
                  acc[i][2]+bias0.z, acc[i][3]+bias0.w };
    float4 o1 = { acc[i][4]+bias1.x, acc[i][5]+bias1.y,
                  acc[i][6]+bias1.z, acc[i][7]+bias1.w };
    *(float4*)(C + (size_t)(row0+i)*N + col0)     = o0;
    *(float4*)(C + (size_t)(row0+i)*N + col0 + 4) = o1;
  }
}

// ---------------------------------------------------------------------------
// Rotary (in place). buf: [rows, heads, 128]; pos = row % T_SEQ.
// fp64 trig so angle precision is never the failing term.
// ---------------------------------------------------------------------------
__global__ void rotary_kernel(float* __restrict__ buf, int heads)
{
  const int idx = blockIdx.x * blockDim.x + threadIdx.x;
  const int d = idx & 63;
  const int rh = idx >> 6;
  const int head = rh % heads;
  const int row = rh / heads;
  const int pos = row & (T_SEQ - 1);
  double freq = pow(10000.0, -(double)d / 64.0);
  double ang = (double)pos * freq;
  float cs = (float)cos(ang), sn = (float)sin(ang);
  float* p = buf + ((size_t)row * heads + head) * HDIM + d;
  float x1 = p[0], x2 = p[64];
  p[0]  = x1 * cs - x2 * sn;
  p[64] = x2 * cs + x1 * sn;
}

// ---------------------------------------------------------------------------
// Flash-style MQA attention, fp32, non-causal.
// Block: 256 threads = 64 query rows x 4 lanes. Lane c owns dims {g*16+c*4..+3}.
// K/V tiles (64x128 each) staged in LDS (64 KB). Scores s[64] in registers.
// grid = (T/64, H, B)
// ---------------------------------------------------------------------------
__global__ __launch_bounds__(256) void mqa_flash_kernel(
    const float* __restrict__ qb,   // [B,T,H*128] (rotated)
    const float* __restrict__ kb,   // [B,T,128]   (rotated)
    const float* __restrict__ vb,   // [B,T,128]
    float* __restrict__ ctx)        // [B,T,H*128]
{
  __shared__ float ks[64][128];
  __shared__ float vs[64][128];
  const int tid = threadIdx.x;
  const int qrow = tid >> 2, c = tid & 3;
  const int h = blockIdx.y, b = blockIdx.z;
  const int t = blockIdx.x * 64 + qrow;

  const float* qp = qb + ((size_t)b * T_SEQ + t) * DMODEL + h * HDIM;
  float4 qr[8];
#pragma unroll
  for (int g = 0; g < 8; ++g) qr[g] = *(const float4*)(qp + g*16 + c*4);

  float4 acc4[8];
#pragma unroll
  for (int g = 0; g < 8; ++g) acc4[g] = make_float4(0.f, 0.f, 0.f, 0.f);
  float m = -INFINITY, l = 0.f;
  float s[64];

  for (int kt = 0; kt < T_SEQ/64; ++kt) {
    __syncthreads();   // previous iteration done with ks/vs
    const float* kg = kb + ((size_t)b*T_SEQ + kt*64) * HDIM;
    const float* vg = vb + ((size_t)b*T_SEQ + kt*64) * HDIM;
#pragma unroll
    for (int i = 0; i < 8; ++i) {
      int f = tid + 256*i;          // 0..2047 float4s
      int r = f >> 5, c4 = f & 31;
      *(float4*)&ks[r][c4*4] = *(const float4*)(kg + r*HDIM + c4*4);
      *(float4*)&vs[r][c4*4] = *(const float4*)(vg + r*HDIM + c4*4);
    }
    __syncthreads();

    // pass 1: scores for all 64 keys (partial dot over this lane's 32 dims,
    // then butterfly-reduce across the 4 lanes of the row)
    float tmax = -INFINITY;
#pragma unroll
    for (int j = 0; j < 64; ++j) {
      float p = 0.f;
#pragma unroll
      for (int g = 0; g < 8; ++g) {
        float4 kv = *(const float4*)&ks[j][g*16 + c*4];
        p = fmaf(qr[g].x, kv.x, p);
        p = fmaf(qr[g].y, kv.y, p);
        p = fmaf(qr[g].z, kv.z, p);
        p = fmaf(qr[g].w, kv.w, p);
      }
      p += __shfl_xor(p, 1);
      p += __shfl_xor(p, 2);
      p *= 0.08838834764831845f;    // 1/sqrt(128)
      s[j] = p;
      tmax = fmaxf(tmax, p);
    }

    // online softmax update (identical on all 4 lanes of a row)
    float mnew = fmaxf(m, tmax);
    float alpha = __expf(m - mnew);
    l *= alpha;
#pragma unroll
    for (int j = 0; j < 64; ++j) {
      float p = __expf(s[j] - mnew);
      s[j] = p;
      l += p;
    }
    m = mnew;
#pragma unroll
    for (int g = 0; g < 8; ++g) {
      acc4[g].x *= alpha; acc4[g].y *= alpha;
      acc4[g].z *= alpha; acc4[g].w *= alpha;
    }

    // pass 2: acc += p * V
#pragma unroll
    for (int j = 0; j < 64; ++j) {
      float p = s[j];
#pragma unroll
      for (int g = 0; g < 8; ++g) {
        float4 vv = *(const float4*)&vs[j][g*16 + c*4];
        acc4[g].x = fmaf(p, vv.x, acc4[g].x);
        acc4[g].y = fmaf(p, vv.y, acc4[g].y);
        acc4[g].z = fmaf(p, vv.z, acc4[g].z);
        acc4[g].w = fmaf(p, vv.w, acc4[g].w);
      }
    }
  }

  const float inv = 1.f / l;
  float* op = ctx + ((size_t)b*T_SEQ + t) * DMODEL + h*HDIM;
#pragma unroll
  for (int g = 0; g < 8; ++g) {
    float4 o = make_float4(acc4[g].x*inv, acc4[g].y*inv,
                           acc4[g].z*inv, acc4[g].w*inv);
    *(float4*)(op + g*16 + c*4) = o;
  }
}

// ---------------------------------------------------------------------------
extern "C" void kernel_launch(void* const* d_in, const int* in_sizes, int n_in,
                              void* d_out, int out_size, void* d_ws, size_t ws_size,
                              hipStream_t stream) {
  const float* x  = (const float*)d_in[0];
  const float* Wq = (const float*)d_in[1];
  const float* bq = (const float*)d_in[2];
  const float* Wk = (const float*)d_in[3];
  const float* bk = (const float*)d_in[4];
  const float* Wv = (const float*)d_in[5];
  const float* bv = (const float*)d_in[6];
  const float* Wo = (const float*)d_in[7];
  const float* bo = (const float*)d_in[8];
  float* out = (float*)d_out;

  float* ws   = (float*)d_ws;
  float* qbuf = ws;                         // 4096*2048 = 8.39M floats
  float* cbuf = ws + (size_t)MROWS*DMODEL;  // 8.39M floats
  float* kbuf = cbuf + (size_t)MROWS*DMODEL;// 4096*128
  float* vbuf = kbuf + (size_t)MROWS*HDIM;  // 4096*128
  // total: ~71.3 MB of d_ws

  dim3 blk(256);
  // Q projection: 4096x2048 = x(4096x2048) @ Wq + bq
  gemm_bias_kernel<<<dim3(DMODEL/128, MROWS/128), blk, 0, stream>>>(
      x, Wq, bq, qbuf, MROWS, DMODEL, DMODEL);
  // K/V projections: 4096x128
  gemm_bias_kernel<<<dim3(1, MROWS/128), blk, 0, stream>>>(
      x, Wk, bk, kbuf, MROWS, HDIM, DMODEL);
  gemm_bias_kernel<<<dim3(1, MROWS/128), blk, 0, stream>>>(
      x, Wv, bv, vbuf, MROWS, HDIM, DMODEL);
  // Rotary on Q (16 heads) and K (1 head)
  rotary_kernel<<<(MROWS*NHEADS*64)/256, 256, 0, stream>>>(qbuf, NHEADS);
  rotary_kernel<<<(MROWS*1*64)/256, 256, 0, stream>>>(kbuf, 1);
  // Attention
  mqa_flash_kernel<<<dim3(T_SEQ/64, NHEADS, 2), blk, 0, stream>>>(
      qbuf, kbuf, vbuf, cbuf);
  // Output projection
  gemm_bias_kernel<<<dim3(DMODEL/128, MROWS/128), blk, 0, stream>>>(
      cbuf, Wo, bo, out, MROWS, DMODEL, DMODEL);
}

// Round 2
// 490.268 us; speedup vs baseline: 7.2005x; 7.2005x over previous
//
#include <hip/hip_runtime.h>
#include <math.h>

#define T_SEQ  2048
#define DMODEL 2048
#define NHEADS 16
#define HDIM   128
#define MROWS  4096   // B*T

typedef __attribute__((ext_vector_type(8))) __bf16 bf16x8;
typedef __attribute__((ext_vector_type(4))) __bf16 bf16x4;
typedef __attribute__((ext_vector_type(4))) float f32x4;

// ---------------------------------------------------------------------------
// RoPE table: rope[pos*64+d] = {cos, sin} of pos * 10000^(-d/64). fp64 trig.
// ---------------------------------------------------------------------------
__global__ void build_rope_kernel(float* __restrict__ rope) {
  int idx = blockIdx.x * blockDim.x + threadIdx.x;   // 2048*64
  int d = idx & 63, pos = idx >> 6;
  double freq = pow(10000.0, -(double)d / 64.0);
  double ang = (double)pos * freq;
  rope[idx*2+0] = (float)cos(ang);
  rope[idx*2+1] = (float)sin(ang);
}

// ---------------------------------------------------------------------------
// Elementwise fp32 -> bf16 cast (float4 / bf16x4 vectorized)
// ---------------------------------------------------------------------------
__global__ void cast_bf16_kernel(const float* __restrict__ in,
                                 __bf16* __restrict__ out, int n4) {
  int i = blockIdx.x * blockDim.x + threadIdx.x;
  if (i >= n4) return;
  float4 v = ((const float4*)in)[i];
  bf16x4 o = { (__bf16)v.x, (__bf16)v.y, (__bf16)v.z, (__bf16)v.w };
  *(bf16x4*)(out + (size_t)i*4) = o;
}

// ---------------------------------------------------------------------------
// Transpose-cast: in fp32 [R][C] -> out bf16 [C][R]. 32x32 LDS tile.
// ---------------------------------------------------------------------------
__global__ void transpose_cast_kernel(const float* __restrict__ in,
                                      __bf16* __restrict__ out, int R, int C) {
  __shared__ float t[32][33];
  int tx = threadIdx.x & 31, ty = threadIdx.x >> 5;   // ty 0..7
  int r0 = blockIdx.y*32, c0 = blockIdx.x*32;
#pragma unroll
  for (int i = 0; i < 4; ++i)
    t[ty + i*8][tx] = in[(size_t)(r0 + ty + i*8)*C + c0 + tx];
  __syncthreads();
#pragma unroll
  for (int i = 0; i < 4; ++i)
    out[(size_t)(c0 + ty + i*8)*R + r0 + tx] = (__bf16)t[tx][ty + i*8];
}

// ---------------------------------------------------------------------------
// Rotary + cast: in fp32 [rows][heads*128] -> out bf16 same layout.
// pos = row % T_SEQ. Reads the precomputed rope table.
// ---------------------------------------------------------------------------
__global__ void rotary_cast_kernel(const float* __restrict__ in,
                                   const float* __restrict__ rope,
                                   __bf16* __restrict__ out, int heads) {
  int idx = blockIdx.x * blockDim.x + threadIdx.x;
  int d = idx & 63, rh = idx >> 6;
  int head = rh % heads, row = rh / heads;
  int pos = row & (T_SEQ - 1);
  float2 cs = *(const float2*)(rope + ((size_t)pos*64 + d)*2);
  size_t base = ((size_t)row*heads + head)*HDIM + d;
  float x1 = in[base], x2 = in[base + 64];
  out[base]      = (__bf16)(x1*cs.x - x2*cs.y);
  out[base + 64] = (__bf16)(x2*cs.x + x1*cs.y);
}

// ---------------------------------------------------------------------------
// bf16 MFMA GEMM, 128x128 tile, BK=32. A[M,K] bf16, Bt[N,K] bf16 (pre-
// transposed weights), C[M,N] fp32 = A@B + bias.
// 4 waves, each computes a 64x64 quadrant as 4x4 MFMA tiles (16x16x32).
// LDS rows padded to 40 elems (80B): b128 fragment reads are 2-way max.
// ---------------------------------------------------------------------------
__global__ __launch_bounds__(256) void gemm_bf16_t128(
    const __bf16* __restrict__ A, const __bf16* __restrict__ Bt,
    const float* __restrict__ bias, float* __restrict__ C,
    int M, int N, int K)
{
  constexpr int LD = 40;
  __shared__ __bf16 As[128*LD];
  __shared__ __bf16 Bs[128*LD];
  const int tid = threadIdx.x;
  const int lane = tid & 63, wave = tid >> 6;
  const int quad = lane >> 4, l16 = lane & 15;
  const int m0 = (wave & 1)*64, n0 = (wave >> 1)*64;
  const int row0 = blockIdx.y*128, col0 = blockIdx.x*128;
  const int sr = tid >> 2, sk = (tid & 3)*8;   // staging: row, k-offset

  f32x4 acc[4][4];
#pragma unroll
  for (int i = 0; i < 4; ++i)
#pragma unroll
    for (int j = 0; j < 4; ++j) acc[i][j] = (f32x4){0.f,0.f,0.f,0.f};

  const __bf16* Ag0 = A  + (size_t)(row0 + sr)*K + sk;
  const __bf16* Ag1 = A  + (size_t)(row0 + sr + 64)*K + sk;
  const __bf16* Bg0 = Bt + (size_t)(col0 + sr)*K + sk;
  const __bf16* Bg1 = Bt + (size_t)(col0 + sr + 64)*K + sk;

  for (int kk = 0; kk < K; kk += 32) {
    bf16x8 a0 = *(const bf16x8*)(Ag0 + kk);
    bf16x8 a1 = *(const bf16x8*)(Ag1 + kk);
    bf16x8 b0 = *(const bf16x8*)(Bg0 + kk);
    bf16x8 b1 = *(const bf16x8*)(Bg1 + kk);
    __syncthreads();
    *(bf16x8*)&As[sr*LD + sk]      = a0;
    *(bf16x8*)&As[(sr+64)*LD + sk] = a1;
    *(bf16x8*)&Bs[sr*LD + sk]      = b0;
    *(bf16x8*)&Bs[(sr+64)*LD + sk] = b1;
    __syncthreads();
    bf16x8 af[4], bfr[4];
#pragma unroll
    for (int i = 0; i < 4; ++i)
      af[i] = *(const bf16x8*)&As[(m0 + i*16 + l16)*LD + quad*8];
#pragma unroll
    for (int j = 0; j < 4; ++j)
      bfr[j] = *(const bf16x8*)&Bs[(n0 + j*16 + l16)*LD + quad*8];
#pragma unroll
    for (int i = 0; i < 4; ++i)
#pragma unroll
      for (int j = 0; j < 4; ++j)
        acc[i][j] = __builtin_amdgcn_mfma_f32_16x16x32_bf16(af[i], bfr[j], acc[i][j], 0,0,0);
  }
#pragma unroll
  for (int j = 0; j < 4; ++j) {
    const int ccol = col0 + n0 + j*16 + l16;
    const float bv = bias[ccol];
#pragma unroll
    for (int i = 0; i < 4; ++i) {
      const int crow = row0 + m0 + i*16 + quad*4;
#pragma unroll
      for (int r = 0; r < 4; ++r)
        C[(size_t)(crow + r)*N + ccol] = acc[i][j][r] + bv;
    }
  }
}

// ---------------------------------------------------------------------------
// bf16 MFMA GEMM, 64x64 tile (for the skinny N=128 K/V projections: gives
// 128 blocks instead of 32 -> better CU coverage).
// ---------------------------------------------------------------------------
__global__ __launch_bounds__(256) void gemm_bf16_t64(
    const __bf16* __restrict__ A, const __bf16* __restrict__ Bt,
    const float* __restrict__ bias, float* __restrict__ C,
    int M, int N, int K)
{
  constexpr int LD = 40;
  __shared__ __bf16 As[64*LD];
  __shared__ __bf16 Bs[64*LD];
  const int tid = threadIdx.x;
  const int lane = tid & 63, wave = tid >> 6;
  const int quad = lane >> 4, l16 = lane & 15;
  const int m0 = (wave & 1)*32, n0 = (wave >> 1)*32;
  const int row0 = blockIdx.y*64, col0 = blockIdx.x*64;
  const int sr = tid >> 2, sk = (tid & 3)*8;

  f32x4 acc[2][2];
#pragma unroll
  for (int i = 0; i < 2; ++i)
#pragma unroll
    for (int j = 0; j < 2; ++j) acc[i][j] = (f32x4){0.f,0.f,0.f,0.f};

  const __bf16* Ag = A  + (size_t)(row0 + sr)*K + sk;
  const __bf16* Bg = Bt + (size_t)(col0 + sr)*K + sk;

  for (int kk = 0; kk < K; kk += 32) {
    bf16x8 a0 = *(const bf16x8*)(Ag + kk);
    bf16x8 b0 = *(const bf16x8*)(Bg + kk);
    __syncthreads();
    *(bf16x8*)&As[sr*LD + sk] = a0;
    *(bf16x8*)&Bs[sr*LD + sk] = b0;
    __syncthreads();
    bf16x8 af[2], bfr[2];
#pragma unroll
    for (int i = 0; i < 2; ++i)
      af[i] = *(const bf16x8*)&As[(m0 + i*16 + l16)*LD + quad*8];
#pragma unroll
    for (int j = 0; j < 2; ++j)
      bfr[j] = *(const bf16x8*)&Bs[(n0 + j*16 + l16)*LD + quad*8];
#pragma unroll
    for (int i = 0; i < 2; ++i)
#pragma unroll
      for (int j = 0; j < 2; ++j)
        acc[i][j] = __builtin_amdgcn_mfma_f32_16x16x32_bf16(af[i], bfr[j], acc[i][j], 0,0,0);
  }
#pragma unroll
  for (int j = 0; j < 2; ++j) {
    const int ccol = col0 + n0 + j*16 + l16;
    const float bv = bias[ccol];
#pragma unroll
    for (int i = 0; i < 2; ++i) {
      const int crow = row0 + m0 + i*16 + quad*4;
#pragma unroll
      for (int r = 0; r < 4; ++r)
        C[(size_t)(crow + r)*N + ccol] = acc[i][j][r] + bv;
    }
  }
}

// ---------------------------------------------------------------------------
// MFMA flash MQA attention. Block = 256 thr = 4 waves; wave owns 16 queries.
// Per 64-key tile: S = Q@K^T via mfma (K natural layout IS B-operand layout),
// fp32 online softmax in registers (row = quad*4+reg), P relayout through
// per-wave LDS (C/D-layout -> A-layout, m120's verified transform),
// ctx += P@V via mfma with V pre-transposed globally ([B][128][T]).
// LDS strides padded (136/72/72) to keep b128 reads ~2-way.
// grid = (T/64, H, B)
// ---------------------------------------------------------------------------
#define KSTR 136
#define VSTR 72
#define PSTR 72
__global__ __launch_bounds__(256) void mqa_attn_mfma(
    const __bf16* __restrict__ qb,   // [B*T][2048] rotated bf16
    const __bf16* __restrict__ kb,   // [B*T][128]  rotated bf16
    const __bf16* __restrict__ vt,   // [B][128][T] bf16 (transposed V)
    float* __restrict__ ctx)         // [B*T][2048] fp32
{
  __shared__ __bf16 Ks[64*KSTR];     // 17408 B
  __shared__ __bf16 Vs[128*VSTR];    // 18432 B
  __shared__ __bf16 Ps[4][16*PSTR];  //  9216 B
  const int tid = threadIdx.x, lane = tid & 63, wave = tid >> 6;
  const int quad = lane >> 4, l16 = lane & 15;
  const int h = blockIdx.y, b = blockIdx.z;
  const int qw = blockIdx.x*64 + wave*16;

  // Q fragments (A-operand: Q[m=l16][k=quad*8+j]), loaded once from global
  bf16x8 qf[4];
  const __bf16* qp = qb + ((size_t)b*T_SEQ + qw + l16)*DMODEL + h*HDIM;
#pragma unroll
  for (int ds = 0; ds < 4; ++ds) qf[ds] = *(const bf16x8*)(qp + ds*32 + quad*8);

  f32x4 o[8];
#pragma unroll
  for (int dt = 0; dt < 8; ++dt) o[dt] = (f32x4){0.f,0.f,0.f,0.f};
  float mr[4] = {-INFINITY,-INFINITY,-INFINITY,-INFINITY};
  float lr[4] = {0.f,0.f,0.f,0.f};

  const __bf16* kbase = kb + (size_t)b*T_SEQ*HDIM;
  const __bf16* vbase = vt + (size_t)b*HDIM*T_SEQ;
  const float scale = 0.08838834764831845f;  // 1/sqrt(128)

  for (int kt = 0; kt < T_SEQ/64; ++kt) {
    __syncthreads();
    // stage K tile: Ks[key][d], 64x128 bf16
#pragma unroll
    for (int p = 0; p < 4; ++p) {
      int c = p*256 + tid;
      int key = c >> 4, doff = (c & 15)*8;
      *(bf16x8*)&Ks[key*KSTR + doff] =
          *(const bf16x8*)(kbase + (size_t)(kt*64 + key)*HDIM + doff);
    }
    // stage V tile transposed: Vs[d][key], 128x64 bf16 (from global V^T)
#pragma unroll
    for (int p = 0; p < 4; ++p) {
      int c = p*256 + tid;
      int d = c >> 3, ko = (c & 7)*8;
      *(bf16x8*)&Vs[d*VSTR + ko] =
          *(const bf16x8*)(vbase + (size_t)d*T_SEQ + kt*64 + ko);
    }
    __syncthreads();

    // S = Q @ K^T : b-operand frag = K[key=l16+j*16][d=ds*32+quad*8..+7]
    f32x4 s[4];
#pragma unroll
    for (int j = 0; j < 4; ++j) {
      s[j] = (f32x4){0.f,0.f,0.f,0.f};
#pragma unroll
      for (int ds = 0; ds < 4; ++ds) {
        bf16x8 kf = *(const bf16x8*)&Ks[(j*16 + l16)*KSTR + ds*32 + quad*8];
        s[j] = __builtin_amdgcn_mfma_f32_16x16x32_bf16(qf[ds], kf, s[j], 0,0,0);
      }
    }
    // online softmax; s[j][r] is row (quad*4+r), col (j*16+l16)
    float tmax[4] = {-INFINITY,-INFINITY,-INFINITY,-INFINITY};
#pragma unroll
    for (int j = 0; j < 4; ++j)
#pragma unroll
      for (int r = 0; r < 4; ++r) {
        s[j][r] *= scale;
        tmax[r] = fmaxf(tmax[r], s[j][r]);
      }
#pragma unroll
    for (int off = 1; off < 16; off <<= 1)
#pragma unroll
      for (int r = 0; r < 4; ++r)
        tmax[r] = fmaxf(tmax[r], __shfl_xor(tmax[r], off));
    float alpha[4], lsum[4];
#pragma unroll
    for (int r = 0; r < 4; ++r) {
      float mn = fmaxf(mr[r], tmax[r]);
      alpha[r] = __expf(mr[r] - mn);
      mr[r] = mn;
      lsum[r] = 0.f;
    }
#pragma unroll
    for (int j = 0; j < 4; ++j)
#pragma unroll
      for (int r = 0; r < 4; ++r) {
        float pv = __expf(s[j][r] - mr[r]);
        s[j][r] = pv;
        lsum[r] += pv;
      }
#pragma unroll
    for (int off = 1; off < 16; off <<= 1)
#pragma unroll
      for (int r = 0; r < 4; ++r)
        lsum[r] += __shfl_xor(lsum[r], off);
#pragma unroll
    for (int r = 0; r < 4; ++r)
      lr[r] = lr[r]*alpha[r] + lsum[r];
#pragma unroll
    for (int dt = 0; dt < 8; ++dt)
#pragma unroll
      for (int r = 0; r < 4; ++r)
        o[dt][r] *= alpha[r];
    // P relayout: C/D layout -> LDS [query][key] (per-wave private region)
#pragma unroll
    for (int j = 0; j < 4; ++j)
#pragma unroll
      for (int r = 0; r < 4; ++r)
        Ps[wave][(quad*4 + r)*PSTR + j*16 + l16] = (__bf16)s[j][r];
    __asm__ volatile("s_waitcnt lgkmcnt(0)" ::: "memory");
    // PV: a-frag = P[q=l16][key=ks*32+quad*8..], b-frag = V[key][d=l16+dt*16]
    bf16x8 pf[2];
#pragma unroll
    for (int ks = 0; ks < 2; ++ks)
      pf[ks] = *(const bf16x8*)&Ps[wave][l16*PSTR + ks*32 + quad*8];
#pragma unroll
    for (int dt = 0; dt < 8; ++dt) {
#pragma unroll
      for (int ks = 0; ks < 2; ++ks) {
        bf16x8 vf = *(const bf16x8*)&Vs[(dt*16 + l16)*VSTR + ks*32 + quad*8];
        o[dt] = __builtin_amdgcn_mfma_f32_16x16x32_bf16(pf[ks], vf, o[dt], 0,0,0);
      }
    }
  }
  float inv[4];
#pragma unroll
  for (int r = 0; r < 4; ++r) inv[r] = 1.f / lr[r];
  float* op = ctx + ((size_t)b*T_SEQ + qw + quad*4)*DMODEL + h*HDIM + l16;
#pragma unroll
  for (int dt = 0; dt < 8; ++dt)
#pragma unroll
    for (int r = 0; r < 4; ++r)
      op[(size_t)r*DMODEL + dt*16] = o[dt][r]*inv[r];
}

// ---------------------------------------------------------------------------
extern "C" void kernel_launch(void* const* d_in, const int* in_sizes, int n_in,
                              void* d_out, int out_size, void* d_ws, size_t ws_size,
                              hipStream_t stream) {
  const float* x  = (const float*)d_in[0];
  const float* Wq = (const float*)d_in[1];
  const float* bq = (const float*)d_in[2];
  const float* Wk = (const float*)d_in[3];
  const float* bk = (const float*)d_in[4];
  const float* Wv = (const float*)d_in[5];
  const float* bv = (const float*)d_in[6];
  const float* Wo = (const float*)d_in[7];
  const float* bo = (const float*)d_in[8];
  float* out = (float*)d_out;

  uint8_t* ws = (uint8_t*)d_ws;
  // Buffer plan (66.1 MB + 1 MB rope, sequential reuse):
  float*  qbuf = (float*) (ws);              // 33,554,432 B  fp32 Q; later ctx
  __bf16* xb   = (__bf16*)(ws + 33554432);   // 16,777,216 B  bf16 x; later qb; later ctxb
  __bf16* wqt  = (__bf16*)(ws + 50331648);   //  8,388,608 B  Wq^T bf16; later Wo^T
  __bf16* wkt  = (__bf16*)(ws + 58720256);   //    524,288 B
  __bf16* wvt  = (__bf16*)(ws + 59244544);   //    524,288 B
  float*  kbuf = (float*) (ws + 59768832);   //  2,097,152 B  fp32 K
  float*  vbuf = (float*) (ws + 61865984);   //  2,097,152 B  fp32 V
  __bf16* kbb  = (__bf16*)(ws + 63963136);   //  1,048,576 B  bf16 rotated K
  __bf16* vtb  = (__bf16*)(ws + 65011712);   //  1,048,576 B  bf16 V^T
  float*  rope = (float*) (ws + 66060288);   //  1,048,576 B  cos/sin table

  build_rope_kernel<<<512, 256, 0, stream>>>(rope);
  transpose_cast_kernel<<<dim3(64,64), 256, 0, stream>>>(Wq, wqt, 2048, 2048);
  transpose_cast_kernel<<<dim3(4,64),  256, 0, stream>>>(Wk, wkt, 2048, 128);
  transpose_cast_kernel<<<dim3(4,64),  256, 0, stream>>>(Wv, wvt, 2048, 128);
  cast_bf16_kernel<<<8192, 256, 0, stream>>>(x, xb, MROWS*DMODEL/4);

  gemm_bf16_t128<<<dim3(16,32), 256, 0, stream>>>(xb, wqt, bq, qbuf, MROWS, DMODEL, DMODEL);
  gemm_bf16_t64 <<<dim3(2,64),  256, 0, stream>>>(xb, wkt, bk, kbuf, MROWS, HDIM, DMODEL);
  gemm_bf16_t64 <<<dim3(2,64),  256, 0, stream>>>(xb, wvt, bv, vbuf, MROWS, HDIM, DMODEL);

  // Wo^T overwrites wqt (Q-GEMM already consumed it)
  transpose_cast_kernel<<<dim3(64,64), 256, 0, stream>>>(Wo, wqt, 2048, 2048);

  // rotary+cast: qb overwrites xb (K/V GEMMs already consumed it)
  rotary_cast_kernel<<<(MROWS*NHEADS*64)/256, 256, 0, stream>>>(qbuf, rope, xb, NHEADS);
  rotary_cast_kernel<<<(MROWS*64)/256,        256, 0, stream>>>(kbuf, rope, kbb, 1);
  // V^T per batch
  transpose_cast_kernel<<<dim3(4,64), 256, 0, stream>>>(vbuf,              vtb,             2048, 128);
  transpose_cast_kernel<<<dim3(4,64), 256, 0, stream>>>(vbuf + 2048*128,   vtb + 128*2048,  2048, 128);

  // attention: reads qb(xb), kbb, vtb; writes ctx over qbuf (dead)
  mqa_attn_mfma<<<dim3(32,16,2), 256, 0, stream>>>(xb, kbb, vtb, qbuf);

  // ctx -> bf16 over xb (qb dead)
  cast_bf16_kernel<<<8192, 256, 0, stream>>>(qbuf, xb, MROWS*DMODEL/4);
  gemm_bf16_t128<<<dim3(16,32), 256, 0, stream>>>(xb, wqt, bo, out, MROWS, DMODEL, DMODEL);
}

// Round 3
// 384.720 us; speedup vs baseline: 9.1760x; 1.2744x over previous
//
#include <hip/hip_runtime.h>
#include <math.h>

#define T_SEQ  2048
#define DMODEL 2048
#define NHEADS 16
#define HDIM   128
#define MROWS  4096   // B*T

typedef __attribute__((ext_vector_type(8)))  __bf16 bf16x8;
typedef __attribute__((ext_vector_type(4)))  __bf16 bf16x4;
typedef __attribute__((ext_vector_type(4)))  float  f32x4;
typedef __attribute__((ext_vector_type(16))) float  f32x16;

#define GLOBAL_AS __attribute__((address_space(1)))
#define LDS_AS    __attribute__((address_space(3)))
__device__ __forceinline__ void async_copy16(const __bf16* g, __bf16* l) {
  // 16B per lane, LDS dest = wave-uniform base + lane*16 (m97/m104 semantics)
  __builtin_amdgcn_global_load_lds((const GLOBAL_AS void*)g, (LDS_AS void*)l, 16, 0, 0);
}

// ---------------------------------------------------------------------------
// RoPE table: rope[pos*64+d] = {cos, sin}. fp64 trig.
// ---------------------------------------------------------------------------
__global__ void build_rope_kernel(float* __restrict__ rope) {
  int idx = blockIdx.x * blockDim.x + threadIdx.x;   // 2048*64
  int d = idx & 63, pos = idx >> 6;
  double freq = pow(10000.0, -(double)d / 64.0);
  double ang = (double)pos * freq;
  rope[idx*2+0] = (float)cos(ang);
  rope[idx*2+1] = (float)sin(ang);
}

// ---------------------------------------------------------------------------
// fp32 -> bf16 cast
// ---------------------------------------------------------------------------
__global__ void cast_bf16_kernel(const float* __restrict__ in,
                                 __bf16* __restrict__ out, int n4) {
  int i = blockIdx.x * blockDim.x + threadIdx.x;
  if (i >= n4) return;
  float4 v = ((const float4*)in)[i];
  bf16x4 o = { (__bf16)v.x, (__bf16)v.y, (__bf16)v.z, (__bf16)v.w };
  *(bf16x4*)(out + (size_t)i*4) = o;
}

// ---------------------------------------------------------------------------
// Transpose-cast with input row stride: out[c*ostride + r] = bf16(in[r*istride + c])
// r in [0,R), c in [0,C). grid (C/32, R/32)
// ---------------------------------------------------------------------------
__global__ void transpose_cast_kernel(const float* __restrict__ in, int istride,
                                      __bf16* __restrict__ out, int ostride) {
  __shared__ float t[32][33];
  int tx = threadIdx.x & 31, ty = threadIdx.x >> 5;   // ty 0..7
  int r0 = blockIdx.y*32, c0 = blockIdx.x*32;
#pragma unroll
  for (int i = 0; i < 4; ++i)
    t[ty + i*8][tx] = in[(size_t)(r0 + ty + i*8)*istride + c0 + tx];
  __syncthreads();
#pragma unroll
  for (int i = 0; i < 4; ++i)
    out[(size_t)(c0 + ty + i*8)*ostride + r0 + tx] = (__bf16)t[tx][ty + i*8];
}

// ---------------------------------------------------------------------------
// Rotary + scale + cast. in fp32 rows with istride; out bf16 rows with ostride.
// pos = row % T_SEQ. scale folded in (Q gets log2(e)/sqrt(128), K gets 1).
// ---------------------------------------------------------------------------
__global__ void rotary_cast_kernel(const float* __restrict__ in, int istride,
                                   const float* __restrict__ rope,
                                   __bf16* __restrict__ out, int ostride,
                                   int heads, float scale) {
  int idx = blockIdx.x * blockDim.x + threadIdx.x;
  int d = idx & 63, rh = idx >> 6;
  int head = rh % heads, row = rh / heads;
  int pos = row & (T_SEQ - 1);
  float2 cs = *(const float2*)(rope + ((size_t)pos*64 + d)*2);
  size_t bi = (size_t)row*istride + head*HDIM + d;
  size_t bo = (size_t)row*ostride + head*HDIM + d;
  float x1 = in[bi], x2 = in[bi + 64];
  out[bo]      = (__bf16)((x1*cs.x - x2*cs.y) * scale);
  out[bo + 64] = (__bf16)((x2*cs.x + x1*cs.y) * scale);
}

// ---------------------------------------------------------------------------
// m97-style bf16 MFMA GEMM: 128x128 tile, BK=32, global_load_lds staging,
// unpadded LDS [row][32]. A[M,K], Bt[N,K], C = A@B + bias (fp32).
// ---------------------------------------------------------------------------
__global__ __launch_bounds__(256) void gemm_bf16_t128(
    const __bf16* __restrict__ A, const __bf16* __restrict__ Bt,
    const float* __restrict__ bias, float* __restrict__ C,
    int M, int N, int K)
{
  __shared__ __bf16 As[128*32];
  __shared__ __bf16 Bs[128*32];
  const int tid = threadIdx.x;
  const int lane = tid & 63, wave = tid >> 6;
  const int quad = lane >> 4, l16 = lane & 15;
  const int m0 = (wave & 1)*64, n0 = (wave >> 1)*64;
  const int row0 = blockIdx.y*128, col0 = blockIdx.x*128;
  const int srow = lane >> 2, scol = (lane & 3)*8;

  f32x4 acc[4][4];
#pragma unroll
  for (int i = 0; i < 4; ++i)
#pragma unroll
    for (int j = 0; j < 4; ++j) acc[i][j] = (f32x4){0.f,0.f,0.f,0.f};

  // staging sources: wave w covers rows [32w,32w+32) in two 16-row calls
  const __bf16* Ag = A  + (size_t)(row0 + wave*32 + srow)*K + scol;
  const __bf16* Bg = Bt + (size_t)(col0 + wave*32 + srow)*K + scol;
  __bf16* AsW = &As[wave*1024];
  __bf16* BsW = &Bs[wave*1024];

  for (int kk = 0; kk < K; kk += 32) {
    __syncthreads();
    async_copy16(Ag + kk,              AsW);
    async_copy16(Ag + kk + (size_t)16*K, AsW + 512);
    async_copy16(Bg + kk,              BsW);
    async_copy16(Bg + kk + (size_t)16*K, BsW + 512);
    __syncthreads();
    bf16x8 af[4], bfr[4];
#pragma unroll
    for (int i = 0; i < 4; ++i)
      af[i] = *(const bf16x8*)&As[(m0 + i*16 + l16)*32 + quad*8];
#pragma unroll
    for (int j = 0; j < 4; ++j)
      bfr[j] = *(const bf16x8*)&Bs[(n0 + j*16 + l16)*32 + quad*8];
#pragma unroll
    for (int i = 0; i < 4; ++i)
#pragma unroll
      for (int j = 0; j < 4; ++j)
        acc[i][j] = __builtin_amdgcn_mfma_f32_16x16x32_bf16(af[i], bfr[j], acc[i][j], 0,0,0);
  }
#pragma unroll
  for (int j = 0; j < 4; ++j) {
    const int ccol = col0 + n0 + j*16 + l16;
    const float bv = bias[ccol];
#pragma unroll
    for (int i = 0; i < 4; ++i) {
      const int crow = row0 + m0 + i*16 + quad*4;
#pragma unroll
      for (int r = 0; r < 4; ++r)
        C[(size_t)(crow + r)*N + ccol] = acc[i][j][r] + bv;
    }
  }
}

// ---------------------------------------------------------------------------
// Fused K/V projection GEMM: tile 16(M) x 256(N), BK=32, global_load_lds.
// Bt = [256][2048] (Wk^T rows 0..127, Wv^T rows 128..255).
// C[4096][256] fp32; bias from bk (col<128) or bv. grid (1, 256).
// ---------------------------------------------------------------------------
__global__ __launch_bounds__(256) void gemm_kv_t16(
    const __bf16* __restrict__ A, const __bf16* __restrict__ Bt,
    const float* __restrict__ bk, const float* __restrict__ bv,
    float* __restrict__ C, int K)
{
  __shared__ __bf16 As[16*32];
  __shared__ __bf16 Bs[256*32];
  const int tid = threadIdx.x;
  const int lane = tid & 63, wave = tid >> 6;
  const int quad = lane >> 4, l16 = lane & 15;
  const int row0 = blockIdx.y*16;
  const int srow = lane >> 2, scol = (lane & 3)*8;

  f32x4 acc[4];
#pragma unroll
  for (int j = 0; j < 4; ++j) acc[j] = (f32x4){0.f,0.f,0.f,0.f};

  const __bf16* Ag = A + (size_t)(row0 + srow)*K + scol;
  const __bf16* Bg = Bt + (size_t)(wave*64 + srow)*K + scol;   // wave covers rows [64w,64w+64)

  for (int kk = 0; kk < K; kk += 32) {
    __syncthreads();
    if (wave == 0) async_copy16(Ag + kk, &As[0]);
#pragma unroll
    for (int c = 0; c < 4; ++c)
      async_copy16(Bg + kk + (size_t)(c*16)*K, &Bs[(wave*4 + c)*512]);
    __syncthreads();
    bf16x8 af = *(const bf16x8*)&As[l16*32 + quad*8];
#pragma unroll
    for (int j = 0; j < 4; ++j) {
      bf16x8 bfr = *(const bf16x8*)&Bs[(wave*64 + j*16 + l16)*32 + quad*8];
      acc[j] = __builtin_amdgcn_mfma_f32_16x16x32_bf16(af, bfr, acc[j], 0,0,0);
    }
  }
#pragma unroll
  for (int j = 0; j < 4; ++j) {
    const int ccol = wave*64 + j*16 + l16;
    const float bias = (ccol < 128) ? bk[ccol] : bv[ccol - 128];
#pragma unroll
    for (int r = 0; r < 4; ++r)
      C[(size_t)(row0 + quad*4 + r)*256 + ccol] = acc[j][r] + bias;
  }
}

// ---------------------------------------------------------------------------
// MFMA flash MQA attention, 32x32x16, S^T formulation, no-max exp2 softmax.
// Block = 256 thr = 4 waves; wave owns 32 queries; block = 128 queries.
// Per 64-key tile:
//   S^T = K·Q^T  (A=K-frag from LDS, B=Q-frag in regs)  -> lane owns 1 query col
//   P = exp2(S^T) (scale*log2e folded into Q), lsum accumulated per lane
//   P packed to LDS [q][key] via bf16x4 ds_write_b64 (4 consecutive keys/reg-group)
//   O += P@V^T    (A=P from LDS, B=V^T-frag)
// LDS strides 136/72/72: bank slot (l32+c)%8 -> balanced (conflict-free).
// grid = (T/128, H, B)
// ---------------------------------------------------------------------------
#define KSTR 136
#define VSTR 72
#define PSTR 72
__global__ __launch_bounds__(256) void mqa_attn_mfma(
    const __bf16* __restrict__ qb,   // [B*T][2048] rotated+scaled bf16
    const __bf16* __restrict__ kb,   // [B*T][128]  rotated bf16
    const __bf16* __restrict__ vt,   // [B][128][T] bf16 (V^T)
    float* __restrict__ ctx)         // [B*T][2048] fp32
{
  __shared__ __bf16 Ks[64*KSTR];     // 17408 B
  __shared__ __bf16 Vs[128*VSTR];    // 18432 B
  __shared__ __bf16 Ps[4][32*PSTR];  // 18432 B
  __shared__ float  Linv[128];       //   512 B
  const int tid = threadIdx.x, lane = tid & 63, wave = tid >> 6;
  const int h5 = lane >> 5, l32 = lane & 31;
  const int h = blockIdx.y, b = blockIdx.z;
  const int qbase = blockIdx.x*128 + wave*32;

  // Q as B-operand fragments: B[k=h5*8+j][n=l32] = Q[q=l32][d=ds*16+h5*8+j]
  bf16x8 qf[8];
  const __bf16* qp = qb + ((size_t)b*T_SEQ + qbase + l32)*DMODEL + h*HDIM;
#pragma unroll
  for (int ds = 0; ds < 8; ++ds) qf[ds] = *(const bf16x8*)(qp + ds*16 + h5*8);

  f32x16 oacc[4];
#pragma unroll
  for (int g = 0; g < 4; ++g)
#pragma unroll
    for (int r = 0; r < 16; ++r) oacc[g][r] = 0.f;
  float lsum = 0.f;

  const __bf16* kbase = kb + (size_t)b*T_SEQ*HDIM;
  const __bf16* vbase = vt + (size_t)b*HDIM*T_SEQ;

  for (int kt = 0; kt < T_SEQ/64; ++kt) {
    __syncthreads();
    // stage K tile: Ks[key][d] (64x128), fully coalesced 16B chunks
#pragma unroll
    for (int i = 0; i < 4; ++i) {
      int idx = i*256 + tid;            // 1024 chunks
      int key = idx >> 4, c = idx & 15;
      *(bf16x8*)&Ks[key*KSTR + c*8] =
          *(const bf16x8*)(kbase + (size_t)(kt*64 + key)*HDIM + c*8);
    }
    // stage V^T tile: Vs[d][key] (128x64)
#pragma unroll
    for (int i = 0; i < 4; ++i) {
      int idx = i*256 + tid;
      int d = idx >> 3, c = idx & 7;
      *(bf16x8*)&Vs[d*VSTR + c*8] =
          *(const bf16x8*)(vbase + (size_t)d*T_SEQ + kt*64 + c*8);
    }
    __syncthreads();

    // S^T = K·Q^T, two 32-key groups
    f32x16 sacc[2];
#pragma unroll
    for (int kg = 0; kg < 2; ++kg) {
#pragma unroll
      for (int r = 0; r < 16; ++r) sacc[kg][r] = 0.f;
#pragma unroll
      for (int ds = 0; ds < 8; ++ds) {
        bf16x8 kf = *(const bf16x8*)&Ks[(kg*32 + l32)*KSTR + ds*16 + h5*8];
        sacc[kg] = __builtin_amdgcn_mfma_f32_32x32x16_bf16(kf, qf[ds], sacc[kg], 0,0,0);
      }
    }
    // exp2 softmax (no max subtraction; scale*log2e already in Q).
    // lane owns query col q=l32, keys {kg*32 + r0 + 8*r1 + 4*h5}.
#pragma unroll
    for (int kg = 0; kg < 2; ++kg)
#pragma unroll
      for (int r1 = 0; r1 < 4; ++r1) {
        bf16x4 pk;
#pragma unroll
        for (int r0 = 0; r0 < 4; ++r0) {
          float p = __builtin_amdgcn_exp2f(sacc[kg][r1*4 + r0]);
          lsum += p;
          pk[r0] = (__bf16)p;
        }
        *(bf16x4*)&Ps[wave][l32*PSTR + kg*32 + r1*8 + h5*4] = pk;
      }
    __asm__ volatile("s_waitcnt lgkmcnt(0)" ::: "memory");
    // O += P@V^T : A = P[q=l32][k], B = V[key][d=l32]
#pragma unroll
    for (int ks = 0; ks < 4; ++ks) {
      bf16x8 pf = *(const bf16x8*)&Ps[wave][l32*PSTR + ks*16 + h5*8];
#pragma unroll
      for (int g = 0; g < 4; ++g) {
        bf16x8 vf = *(const bf16x8*)&Vs[(g*32 + l32)*VSTR + ks*16 + h5*8];
        oacc[g] = __builtin_amdgcn_mfma_f32_32x32x16_bf16(pf, vf, oacc[g], 0,0,0);
      }
    }
  }

  // finalize: combine the two key-halves of each query column, invert, share
  lsum += __shfl_xor(lsum, 32);
  if (h5 == 0) Linv[wave*32 + l32] = 1.f / lsum;
  __asm__ volatile("s_waitcnt lgkmcnt(0)" ::: "memory");

  float* op = ctx + ((size_t)b*T_SEQ + qbase)*DMODEL + h*HDIM + l32;
#pragma unroll
  for (int r1 = 0; r1 < 4; ++r1) {
    float4 iv = *(const float4*)&Linv[wave*32 + r1*8 + h5*4];
#pragma unroll
    for (int r0 = 0; r0 < 4; ++r0) {
      int qrow = r1*8 + h5*4 + r0;
#pragma unroll
      for (int g = 0; g < 4; ++g) {
        float v = oacc[g][r1*4 + r0] * (&iv.x)[r0];
        op[(size_t)qrow*DMODEL + g*32] = v;
      }
    }
  }
}

// ---------------------------------------------------------------------------
extern "C" void kernel_launch(void* const* d_in, const int* in_sizes, int n_in,
                              void* d_out, int out_size, void* d_ws, size_t ws_size,
                              hipStream_t stream) {
  const float* x  = (const float*)d_in[0];
  const float* Wq = (const float*)d_in[1];
  const float* bq = (const float*)d_in[2];
  const float* Wk = (const float*)d_in[3];
  const float* bk = (const float*)d_in[4];
  const float* Wv = (const float*)d_in[5];
  const float* bv = (const float*)d_in[6];
  const float* Wo = (const float*)d_in[7];
  const float* bo = (const float*)d_in[8];
  float* out = (float*)d_out;

  uint8_t* ws = (uint8_t*)d_ws;
  float*  qbuf = (float*) (ws);              // 33.5 MB fp32 Q; later ctx
  __bf16* xb   = (__bf16*)(ws + 33554432);   // 16.8 MB bf16 x; later qbb; later ctxb
  __bf16* wqt  = (__bf16*)(ws + 50331648);   //  8.4 MB Wq^T; later Wo^T
  __bf16* wkvt = (__bf16*)(ws + 58720256);   //  1.0 MB [256][2048] Wk^T|Wv^T
  float*  kvbuf= (float*) (ws + 59768832);   //  4.2 MB fp32 [4096][256] K|V
  __bf16* kbb  = (__bf16*)(ws + 63963136);   //  1.0 MB bf16 rotated K
  __bf16* vtb  = (__bf16*)(ws + 65011712);   //  1.0 MB bf16 V^T [B][128][T]
  float*  rope = (float*) (ws + 66060288);   //  1.0 MB cos/sin table

  build_rope_kernel<<<512, 256, 0, stream>>>(rope);
  transpose_cast_kernel<<<dim3(64,64), 256, 0, stream>>>(Wq, 2048, wqt, 2048);
  transpose_cast_kernel<<<dim3(4,64),  256, 0, stream>>>(Wk, 128,  wkvt, 2048);
  transpose_cast_kernel<<<dim3(4,64),  256, 0, stream>>>(Wv, 128,  wkvt + (size_t)128*2048, 2048);
  cast_bf16_kernel<<<8192, 256, 0, stream>>>(x, xb, MROWS*DMODEL/4);

  gemm_bf16_t128<<<dim3(16,32), 256, 0, stream>>>(xb, wqt, bq, qbuf, MROWS, DMODEL, DMODEL);
  gemm_kv_t16<<<dim3(1,256), 256, 0, stream>>>(xb, wkvt, bk, bv, kvbuf, DMODEL);

  // Wo^T overwrites wqt (Q-GEMM consumed it)
  transpose_cast_kernel<<<dim3(64,64), 256, 0, stream>>>(Wo, 2048, wqt, 2048);

  // rotary: Q gets scale = log2(e)/sqrt(128) folded in; overwrites xb (dead)
  const float qscale = 1.4426950408889634f * 0.08838834764831845f;
  rotary_cast_kernel<<<(MROWS*NHEADS*64)/256, 256, 0, stream>>>(
      qbuf, DMODEL, rope, xb, DMODEL, NHEADS, qscale);
  rotary_cast_kernel<<<(MROWS*64)/256, 256, 0, stream>>>(
      kvbuf, 256, rope, kbb, HDIM, 1, 1.0f);
  // V^T per batch from kvbuf cols 128..255 (row stride 256)
  transpose_cast_kernel<<<dim3(4,64), 256, 0, stream>>>(
      kvbuf + 128, 256, vtb, T_SEQ);
  transpose_cast_kernel<<<dim3(4,64), 256, 0, stream>>>(
      kvbuf + (size_t)2048*256 + 128, 256, vtb + (size_t)HDIM*T_SEQ, T_SEQ);

  // attention: reads xb (rotated Q), kbb, vtb; writes ctx over qbuf (dead)
  mqa_attn_mfma<<<dim3(16,16,2), 256, 0, stream>>>(xb, kbb, vtb, qbuf);

  // ctx -> bf16 over xb (rotated Q dead)
  cast_bf16_kernel<<<8192, 256, 0, stream>>>(qbuf, xb, MROWS*DMODEL/4);
  gemm_bf16_t128<<<dim3(16,32), 256, 0, stream>>>(xb, wqt, bo, out, MROWS, DMODEL, DMODEL);
}

// Round 4
// 314.038 us; speedup vs baseline: 11.2412x; 1.2251x over previous
//
#include <hip/hip_runtime.h>
#include <math.h>

#define T_SEQ  2048
#define DMODEL 2048
#define NHEADS 16
#define HDIM   128
#define MROWS  4096   // B*T

typedef __attribute__((ext_vector_type(8)))  __bf16 bf16x8;
typedef __attribute__((ext_vector_type(4)))  __bf16 bf16x4;
typedef __attribute__((ext_vector_type(4)))  float  f32x4;
typedef __attribute__((ext_vector_type(16))) float  f32x16;

#define GLOBAL_AS __attribute__((address_space(1)))
#define LDS_AS    __attribute__((address_space(3)))
__device__ __forceinline__ void async_copy16(const __bf16* g, __bf16* l) {
  // 16B/lane, LDS dest = wave-uniform base + lane*16 (m97/m104 semantics)
  __builtin_amdgcn_global_load_lds((const GLOBAL_AS void*)g, (LDS_AS void*)l, 16, 0, 0);
}

// ---------------------------------------------------------------------------
// RoPE table: rope[pos*64+d] = {cos, sin}. fp64 trig (one-time, 131k entries).
// ---------------------------------------------------------------------------
__global__ void build_rope_kernel(float2* __restrict__ rope) {
  int idx = blockIdx.x * blockDim.x + threadIdx.x;   // 2048*64
  int d = idx & 63, pos = idx >> 6;
  double freq = pow(10000.0, -(double)d / 64.0);
  double ang = (double)pos * freq;
  rope[idx] = make_float2((float)cos(ang), (float)sin(ang));
}

// ---------------------------------------------------------------------------
// fp32 -> bf16 cast
// ---------------------------------------------------------------------------
__global__ void cast_bf16_kernel(const float* __restrict__ in,
                                 __bf16* __restrict__ out, int n4) {
  int i = blockIdx.x * blockDim.x + threadIdx.x;
  if (i >= n4) return;
  float4 v = ((const float4*)in)[i];
  bf16x4 o = { (__bf16)v.x, (__bf16)v.y, (__bf16)v.z, (__bf16)v.w };
  *(bf16x4*)(out + (size_t)i*4) = o;
}

// ---------------------------------------------------------------------------
// Combined weight transpose-cast: Wq|Wk|Wv -> wqkvt [2304][2048],
// Wo -> wot [2048][2048]. One launch, region by blockIdx.x.
// ---------------------------------------------------------------------------
__global__ void wtrans_kernel(const float* __restrict__ Wq,
                              const float* __restrict__ Wk,
                              const float* __restrict__ Wv,
                              const float* __restrict__ Wo,
                              __bf16* __restrict__ wqkvt,
                              __bf16* __restrict__ wot) {
  __shared__ float t[32][33];
  const int bx = blockIdx.x;            // 0..135
  const float* src; __bf16* dst; int istride, c0, orow;
  if (bx < 64)       { src = Wq; istride = 2048; c0 = bx*32;      orow = c0;        dst = wqkvt; }
  else if (bx < 68)  { src = Wk; istride = 128;  c0 = (bx-64)*32; orow = 2048 + c0; dst = wqkvt; }
  else if (bx < 72)  { src = Wv; istride = 128;  c0 = (bx-68)*32; orow = 2176 + c0; dst = wqkvt; }
  else               { src = Wo; istride = 2048; c0 = (bx-72)*32; orow = c0;        dst = wot; }
  const int tx = threadIdx.x & 31, ty = threadIdx.x >> 5;
  const int r0 = blockIdx.y*32;
#pragma unroll
  for (int i = 0; i < 4; ++i)
    t[ty + i*8][tx] = src[(size_t)(r0 + ty + i*8)*istride + c0 + tx];
  __syncthreads();
#pragma unroll
  for (int i = 0; i < 4; ++i)
    dst[(size_t)(orow + ty + i*8)*2048 + r0 + tx] = (__bf16)t[tx][ty + i*8];
}

// ---------------------------------------------------------------------------
// bf16 -> bf16 transpose for V: in [B][2048][128] -> out [B][128][2048].
// ---------------------------------------------------------------------------
__global__ void transpose_v_kernel(const __bf16* __restrict__ in,
                                   __bf16* __restrict__ out) {
  __shared__ __bf16 t[32][34];
  const int bz = blockIdx.z;
  in  += (size_t)bz * 2048 * 128;
  out += (size_t)bz * 128 * 2048;
  const int tx = threadIdx.x & 31, ty = threadIdx.x >> 5;
  const int r0 = blockIdx.y*32, c0 = blockIdx.x*32;
#pragma unroll
  for (int i = 0; i < 4; ++i)
    t[ty + i*8][tx] = in[(size_t)(r0 + ty + i*8)*128 + c0 + tx];
  __syncthreads();
#pragma unroll
  for (int i = 0; i < 4; ++i)
    out[(size_t)(c0 + ty + i*8)*2048 + r0 + tx] = t[tx][ty + i*8];
}

// ---------------------------------------------------------------------------
// Fused QKV GEMM: C = x @ [Wq|Wk|Wv] + bias, then RoPE (Q,K) + scale (Q) +
// bf16 cast, all in the epilogue. m97-style: 128x128 tile, BK=32,
// global_load_lds staging, unpadded LDS [row][32].
// Column remap: wave quadrant cols = {n0..n0+31} u {n0+64..n0+95}
// (n0=(wave&1)*32) so RoPE pair (d, d+64) = (acc[i][j], acc[i][j+2]) in the
// SAME lane -> register-only rotary, no LDS exchange.
// grid (18, 32): bx 0..15 = Q head bx; bx 16 = K; bx 17 = V.
// ---------------------------------------------------------------------------
__global__ __launch_bounds__(256) void gemm_qkv_fused(
    const __bf16* __restrict__ A,      // xb [4096][2048]
    const __bf16* __restrict__ Bt,     // wqkvt [2304][2048]
    const float* __restrict__ bq, const float* __restrict__ bk,
    const float* __restrict__ bv,
    const float2* __restrict__ rope,   // [2048][64]
    __bf16* __restrict__ qrb,          // [4096][2048]
    __bf16* __restrict__ kbb,          // [4096][128]
    __bf16* __restrict__ vbb,          // [4096][128]
    float qscale)
{
  __shared__ __bf16 As[128*32];
  __shared__ __bf16 Bs[128*32];
  const int tid = threadIdx.x;
  const int lane = tid & 63, wave = tid >> 6;
  const int quad = lane >> 4, l16 = lane & 15;
  const int m0 = (wave >> 1)*64, n0 = (wave & 1)*32;
  const int row0 = blockIdx.y*128, col0 = blockIdx.x*128;
  const int srow = lane >> 2, scol = (lane & 3)*8;

  f32x4 acc[4][4];
#pragma unroll
  for (int i = 0; i < 4; ++i)
#pragma unroll
    for (int j = 0; j < 4; ++j) acc[i][j] = (f32x4){0.f,0.f,0.f,0.f};

  const __bf16* Ag = A  + (size_t)(row0 + wave*32 + srow)*DMODEL + scol;
  const __bf16* Bg = Bt + (size_t)(col0 + wave*32 + srow)*DMODEL + scol;
  __bf16* AsW = &As[wave*1024];
  __bf16* BsW = &Bs[wave*1024];

  for (int kk = 0; kk < DMODEL; kk += 32) {
    __syncthreads();
    async_copy16(Ag + kk,                     AsW);
    async_copy16(Ag + kk + (size_t)16*DMODEL, AsW + 512);
    async_copy16(Bg + kk,                     BsW);
    async_copy16(Bg + kk + (size_t)16*DMODEL, BsW + 512);
    __syncthreads();
    bf16x8 af[4], bfr[4];
#pragma unroll
    for (int i = 0; i < 4; ++i)
      af[i] = *(const bf16x8*)&As[(m0 + i*16 + l16)*32 + quad*8];
#pragma unroll
    for (int j = 0; j < 4; ++j) {
      const int cb = n0 + (j & 1)*16 + (j >> 1)*64;   // remapped column base
      bfr[j] = *(const bf16x8*)&Bs[(cb + l16)*32 + quad*8];
    }
#pragma unroll
    for (int i = 0; i < 4; ++i)
#pragma unroll
      for (int j = 0; j < 4; ++j)
        acc[i][j] = __builtin_amdgcn_mfma_f32_16x16x32_bf16(af[i], bfr[j], acc[i][j], 0,0,0);
  }

  // ---- fused epilogue: bias + RoPE + scale + bf16 store -------------------
  const int bx = blockIdx.x;
  const float* bias_p; float scale; bool rot; __bf16* obase; int ostride;
  if (bx < 16)      { bias_p = bq + bx*128; scale = qscale; rot = true;
                      obase = qrb + bx*128; ostride = 2048; }
  else if (bx == 16){ bias_p = bk; scale = 1.f; rot = true;
                      obase = kbb; ostride = 128; }
  else              { bias_p = bv; scale = 1.f; rot = false;
                      obase = vbb; ostride = 128; }

#pragma unroll
  for (int j = 0; j < 2; ++j) {
    const int d = n0 + j*16 + l16;        // 0..63 within the 128-wide region
    const float b1 = bias_p[d], b2 = bias_p[d + 64];
#pragma unroll
    for (int i = 0; i < 4; ++i) {
      const int rl = m0 + i*16 + quad*4;
#pragma unroll
      for (int r = 0; r < 4; ++r) {
        const int rg = row0 + rl + r;
        const float x1 = acc[i][j][r]   + b1;
        const float x2 = acc[i][j+2][r] + b2;
        float c = 1.f, s = 0.f;
        if (rot) { float2 cs = rope[(size_t)(rg & (T_SEQ-1))*64 + d]; c = cs.x; s = cs.y; }
        obase[(size_t)rg*ostride + d]      = (__bf16)((x1*c - x2*s)*scale);
        obase[(size_t)rg*ostride + d + 64] = (__bf16)((x2*c + x1*s)*scale);
      }
    }
  }
}

// ---------------------------------------------------------------------------
// m97-style bf16 MFMA GEMM (unchanged from R3): C = A@B + bias, fp32 out.
// ---------------------------------------------------------------------------
__global__ __launch_bounds__(256) void gemm_bf16_t128(
    const __bf16* __restrict__ A, const __bf16* __restrict__ Bt,
    const float* __restrict__ bias, float* __restrict__ C,
    int M, int N, int K)
{
  __shared__ __bf16 As[128*32];
  __shared__ __bf16 Bs[128*32];
  const int tid = threadIdx.x;
  const int lane = tid & 63, wave = tid >> 6;
  const int quad = lane >> 4, l16 = lane & 15;
  const int m0 = (wave & 1)*64, n0 = (wave >> 1)*64;
  const int row0 = blockIdx.y*128, col0 = blockIdx.x*128;
  const int srow = lane >> 2, scol = (lane & 3)*8;

  f32x4 acc[4][4];
#pragma unroll
  for (int i = 0; i < 4; ++i)
#pragma unroll
    for (int j = 0; j < 4; ++j) acc[i][j] = (f32x4){0.f,0.f,0.f,0.f};

  const __bf16* Ag = A  + (size_t)(row0 + wave*32 + srow)*K + scol;
  const __bf16* Bg = Bt + (size_t)(col0 + wave*32 + srow)*K + scol;
  __bf16* AsW = &As[wave*1024];
  __bf16* BsW = &Bs[wave*1024];

  for (int kk = 0; kk < K; kk += 32) {
    __syncthreads();
    async_copy16(Ag + kk,              AsW);
    async_copy16(Ag + kk + (size_t)16*K, AsW + 512);
    async_copy16(Bg + kk,              BsW);
    async_copy16(Bg + kk + (size_t)16*K, BsW + 512);
    __syncthreads();
    bf16x8 af[4], bfr[4];
#pragma unroll
    for (int i = 0; i < 4; ++i)
      af[i] = *(const bf16x8*)&As[(m0 + i*16 + l16)*32 + quad*8];
#pragma unroll
    for (int j = 0; j < 4; ++j)
      bfr[j] = *(const bf16x8*)&Bs[(n0 + j*16 + l16)*32 + quad*8];
#pragma unroll
    for (int i = 0; i < 4; ++i)
#pragma unroll
      for (int j = 0; j < 4; ++j)
        acc[i][j] = __builtin_amdgcn_mfma_f32_16x16x32_bf16(af[i], bfr[j], acc[i][j], 0,0,0);
  }
#pragma unroll
  for (int j = 0; j < 4; ++j) {
    const int ccol = col0 + n0 + j*16 + l16;
    const float bvv = bias[ccol];
#pragma unroll
    for (int i = 0; i < 4; ++i) {
      const int crow = row0 + m0 + i*16 + quad*4;
#pragma unroll
      for (int r = 0; r < 4; ++r)
        C[(size_t)(crow + r)*N + ccol] = acc[i][j][r] + bvv;
    }
  }
}

// ---------------------------------------------------------------------------
// MFMA flash MQA attention (R3 core, now writes bf16 ctx directly).
// 32x32x16, S^T formulation, no-max exp2 softmax (scale*log2e folded into Q).
// grid = (T/128, H, B)
// ---------------------------------------------------------------------------
#define KSTR 136
#define VSTR 72
#define PSTR 72
__global__ __launch_bounds__(256) void mqa_attn_mfma(
    const __bf16* __restrict__ qb,   // [B*T][2048] rotated+scaled bf16
    const __bf16* __restrict__ kb,   // [B*T][128]  rotated bf16
    const __bf16* __restrict__ vt,   // [B][128][T] bf16 (V^T)
    __bf16* __restrict__ ctx)        // [B*T][2048] bf16
{
  __shared__ __bf16 Ks[64*KSTR];
  __shared__ __bf16 Vs[128*VSTR];
  __shared__ __bf16 Ps[4][32*PSTR];
  __shared__ float  Linv[128];
  const int tid = threadIdx.x, lane = tid & 63, wave = tid >> 6;
  const int h5 = lane >> 5, l32 = lane & 31;
  const int h = blockIdx.y, b = blockIdx.z;
  const int qbase = blockIdx.x*128 + wave*32;

  bf16x8 qf[8];
  const __bf16* qp = qb + ((size_t)b*T_SEQ + qbase + l32)*DMODEL + h*HDIM;
#pragma unroll
  for (int ds = 0; ds < 8; ++ds) qf[ds] = *(const bf16x8*)(qp + ds*16 + h5*8);

  f32x16 oacc[4];
#pragma unroll
  for (int g = 0; g < 4; ++g)
#pragma unroll
    for (int r = 0; r < 16; ++r) oacc[g][r] = 0.f;
  float lsum = 0.f;

  const __bf16* kbase = kb + (size_t)b*T_SEQ*HDIM;
  const __bf16* vbase = vt + (size_t)b*HDIM*T_SEQ;

  for (int kt = 0; kt < T_SEQ/64; ++kt) {
    __syncthreads();
#pragma unroll
    for (int i = 0; i < 4; ++i) {
      int idx = i*256 + tid;
      int key = idx >> 4, c = idx & 15;
      *(bf16x8*)&Ks[key*KSTR + c*8] =
          *(const bf16x8*)(kbase + (size_t)(kt*64 + key)*HDIM + c*8);
    }
#pragma unroll
    for (int i = 0; i < 4; ++i) {
      int idx = i*256 + tid;
      int d = idx >> 3, c = idx & 7;
      *(bf16x8*)&Vs[d*VSTR + c*8] =
          *(const bf16x8*)(vbase + (size_t)d*T_SEQ + kt*64 + c*8);
    }
    __syncthreads();

    f32x16 sacc[2];
#pragma unroll
    for (int kg = 0; kg < 2; ++kg) {
#pragma unroll
      for (int r = 0; r < 16; ++r) sacc[kg][r] = 0.f;
#pragma unroll
      for (int ds = 0; ds < 8; ++ds) {
        bf16x8 kf = *(const bf16x8*)&Ks[(kg*32 + l32)*KSTR + ds*16 + h5*8];
        sacc[kg] = __builtin_amdgcn_mfma_f32_32x32x16_bf16(kf, qf[ds], sacc[kg], 0,0,0);
      }
    }
#pragma unroll
    for (int kg = 0; kg < 2; ++kg)
#pragma unroll
      for (int r1 = 0; r1 < 4; ++r1) {
        bf16x4 pk;
#pragma unroll
        for (int r0 = 0; r0 < 4; ++r0) {
          float p = __builtin_amdgcn_exp2f(sacc[kg][r1*4 + r0]);
          lsum += p;
          pk[r0] = (__bf16)p;
        }
        *(bf16x4*)&Ps[wave][l32*PSTR + kg*32 + r1*8 + h5*4] = pk;
      }
    __asm__ volatile("s_waitcnt lgkmcnt(0)" ::: "memory");
#pragma unroll
    for (int ks = 0; ks < 4; ++ks) {
      bf16x8 pf = *(const bf16x8*)&Ps[wave][l32*PSTR + ks*16 + h5*8];
#pragma unroll
      for (int g = 0; g < 4; ++g) {
        bf16x8 vf = *(const bf16x8*)&Vs[(g*32 + l32)*VSTR + ks*16 + h5*8];
        oacc[g] = __builtin_amdgcn_mfma_f32_32x32x16_bf16(pf, vf, oacc[g], 0,0,0);
      }
    }
  }

  lsum += __shfl_xor(lsum, 32);
  if (h5 == 0) Linv[wave*32 + l32] = 1.f / lsum;
  __asm__ volatile("s_waitcnt lgkmcnt(0)" ::: "memory");

  __bf16* op = ctx + ((size_t)b*T_SEQ + qbase)*DMODEL + h*HDIM + l32;
#pragma unroll
  for (int r1 = 0; r1 < 4; ++r1) {
    float4 iv = *(const float4*)&Linv[wave*32 + r1*8 + h5*4];
#pragma unroll
    for (int r0 = 0; r0 < 4; ++r0) {
      int qrow = r1*8 + h5*4 + r0;
#pragma unroll
      for (int g = 0; g < 4; ++g)
        op[(size_t)qrow*DMODEL + g*32] = (__bf16)(oacc[g][r1*4 + r0] * (&iv.x)[r0]);
    }
  }
}

// ---------------------------------------------------------------------------
extern "C" void kernel_launch(void* const* d_in, const int* in_sizes, int n_in,
                              void* d_out, int out_size, void* d_ws, size_t ws_size,
                              hipStream_t stream) {
  const float* x  = (const float*)d_in[0];
  const float* Wq = (const float*)d_in[1];
  const float* bq = (const float*)d_in[2];
  const float* Wk = (const float*)d_in[3];
  const float* bk = (const float*)d_in[4];
  const float* Wv = (const float*)d_in[5];
  const float* bv = (const float*)d_in[6];
  const float* Wo = (const float*)d_in[7];
  const float* bo = (const float*)d_in[8];
  float* out = (float*)d_out;

  uint8_t* ws = (uint8_t*)d_ws;
  __bf16* qrb  = (__bf16*)(ws);              // 16.78 MB rotated+scaled Q bf16
  __bf16* xb   = (__bf16*)(ws + 16777216);   // 16.78 MB x bf16; later ctx bf16
  __bf16* wqkvt= (__bf16*)(ws + 33554432);   //  9.44 MB [2304][2048]
  __bf16* wot  = (__bf16*)(ws + 42991616);   //  8.39 MB [2048][2048]
  __bf16* kbb  = (__bf16*)(ws + 51380224);   //  1.05 MB rotated K bf16
  __bf16* vbb  = (__bf16*)(ws + 52428800);   //  1.05 MB V bf16 [4096][128]
  __bf16* vtb  = (__bf16*)(ws + 53477376);   //  1.05 MB V^T bf16 [B][128][T]
  float2* rope = (float2*)(ws + 54525952);   //  1.05 MB cos/sin table

  const float qscale = 1.4426950408889634f * 0.08838834764831845f; // log2e/sqrt(128)

  build_rope_kernel<<<512, 256, 0, stream>>>(rope);
  wtrans_kernel<<<dim3(136,64), 256, 0, stream>>>(Wq, Wk, Wv, Wo, wqkvt, wot);
  cast_bf16_kernel<<<8192, 256, 0, stream>>>(x, xb, MROWS*DMODEL/4);

  gemm_qkv_fused<<<dim3(18,32), 256, 0, stream>>>(
      xb, wqkvt, bq, bk, bv, rope, qrb, kbb, vbb, qscale);

  transpose_v_kernel<<<dim3(4,64,2), 256, 0, stream>>>(vbb, vtb);

  // attention reads qrb/kbb/vtb, writes bf16 ctx over xb (x is dead)
  mqa_attn_mfma<<<dim3(16,16,2), 256, 0, stream>>>(qrb, kbb, vtb, xb);

  gemm_bf16_t128<<<dim3(16,32), 256, 0, stream>>>(xb, wot, bo, out, MROWS, DMODEL, DMODEL);
}